// Round 10
// baseline (180.329 us; speedup 1.0000x reference)
//
#include <hip/hip_runtime.h>
#include <hip/hip_bf16.h>

// ODEFunc CNF dynamics, B=1e6 rows, H=64:
//   h1 = elu(W1 z + b1); [h2|u2|v2] = [h1|u|v] W2^T; out01 = W3 elu(h2)+b3;
//   trace = W3[0,:]*(elu'(h2)*u2) + W3[1,:]*(elu'(h2)*v2); out[:,2] = -trace
//
// R10. Model: R6 (best, 72us kernel) is VALU-issue+latency bound: ~1590
// busy cyc/tile, 44% idle at 2 waves/EU; MFMA floor only ~116 cyc/tile.
// Lever: 3rd wave/EU WITHOUT adding critical-path loads (R8's mistake) or
// liveness (R9's mistake: z-prefetch -> 2.6MB scratch, 92us).
// How: shrink persistent constants to fit the 170-reg 3-wave budget:
//   - layer-1 (w0,w1) and b1 packed bf16x2: 48 -> 24 regs
//   - epilogue (w30,w31) and b2 packed bf16x2: 48 -> 24 regs
//     (bf16->f32 unpack = 1 shift / 1 and; +0.4% rel err, threshold has 4.5x room)
//   - phase1/MFMA interleaved per jt: only 3 B-frags live (24 -> 12 regs)
// Demand ~165 <= 170. Grid 768x256 = 3072 waves = exactly resident at 3/EU.
// MFMA layout (R6-validated): A=W2 block A[m=lane&15][k=quad*8+jj]; B=[h|u|v]^T
// in-register; D[k][row]: row=lane&15, k=mt*16+quad*4+reg; W3-fold in-lane
// over 16 k + 2 shfl_xor stages. No LDS, no spill (watch WRITE_SIZE==11.72MB).

typedef short bf16x8 __attribute__((ext_vector_type(8)));
typedef float f32x4  __attribute__((ext_vector_type(4)));
typedef int   i32x4  __attribute__((ext_vector_type(4)));

#if defined(__has_builtin)
#if __has_builtin(__builtin_amdgcn_cvt_pk_bf16_f32)
#define HAVE_PK_BF16 1
#endif
#endif

#ifdef HAVE_PK_BF16
typedef __bf16 bf16x2_t __attribute__((ext_vector_type(2)));
static __device__ __forceinline__ int f2bf_pk(float a, float b) {
    bf16x2_t r = __builtin_amdgcn_cvt_pk_bf16_f32(a, b);   // lo=a, hi=b
    return __builtin_bit_cast(int, r);
}
#else
static __device__ __forceinline__ int f2bf_pk(float a, float b) {
    unsigned ua = __builtin_bit_cast(unsigned, a);
    unsigned ub = __builtin_bit_cast(unsigned, b);
    ua = (ua + 0x7FFFu + ((ua >> 16) & 1u)) >> 16;
    ub = (ub + 0x7FFFu + ((ub >> 16) & 1u)) & 0xFFFF0000u;
    return (int)(ua | ub);
}
#endif

// bf16 pair -> f32 (exact): lo = shift, hi = mask
static __device__ __forceinline__ float bf_lo(int p) {
    return __builtin_bit_cast(float, (unsigned)p << 16);
}
static __device__ __forceinline__ float bf_hi(int p) {
    return __builtin_bit_cast(float, (unsigned)p & 0xFFFF0000u);
}

__global__ __launch_bounds__(256) __attribute__((amdgpu_waves_per_eu(3, 3)))
void odefunc_mfma(const float* __restrict__ zin,
                  const float* __restrict__ W1, const float* __restrict__ b1,
                  const float* __restrict__ W2, const float* __restrict__ b2,
                  const float* __restrict__ W3, const float* __restrict__ b3,
                  float* __restrict__ out, int B, int ntiles)
{
    const int lane = threadIdx.x & 63;
    const int quad = lane >> 4;      // 0..3
    const int col  = lane & 15;      // row-within-tile (B/D n-index)

    const int wid    = blockIdx.x * (blockDim.x >> 6) + (threadIdx.x >> 6);
    const int nwaves = gridDim.x * (blockDim.x >> 6);

    // ---- Persistent: W2 as A-operand fragments (4 mtiles x 2 jtiles) ----
    bf16x8 aW2[4][2];
#pragma unroll
    for (int mt = 0; mt < 4; ++mt)
#pragma unroll
        for (int jt = 0; jt < 2; ++jt) {
            const float* p = W2 + (mt * 16 + col) * 64 + jt * 32 + quad * 8;
            i32x4 w;
#pragma unroll
            for (int p2 = 0; p2 < 4; ++p2)
                w[p2] = f2bf_pk(p[2 * p2], p[2 * p2 + 1]);
            aW2[mt][jt] = __builtin_bit_cast(bf16x8, w);
        }

    // ---- Persistent, packed bf16: layer-1 consts for this lane's 16 j's ----
    int pkW1[2][8];   // (w0,w1) per j          : 16 regs
    int pkB1[2][4];   // (b1_j0, b1_j1) per pair:  8 regs
#pragma unroll
    for (int jt = 0; jt < 2; ++jt) {
#pragma unroll
        for (int jj = 0; jj < 8; ++jj) {
            int j = jt * 32 + quad * 8 + jj;
            pkW1[jt][jj] = f2bf_pk(W1[2 * j], W1[2 * j + 1]);
        }
#pragma unroll
        for (int p2 = 0; p2 < 4; ++p2) {
            int j = jt * 32 + quad * 8 + 2 * p2;
            pkB1[jt][p2] = f2bf_pk(b1[j], b1[j + 1]);
        }
    }

    // ---- Persistent, packed bf16: epilogue consts for this lane's 16 k's ----
    int pkW3[4][4];   // (W3[0,k], W3[1,k]) per k : 16 regs
    int pkB2[4][2];   // (b2_k0, b2_k1) per pair  :  8 regs
#pragma unroll
    for (int mt = 0; mt < 4; ++mt) {
#pragma unroll
        for (int i = 0; i < 4; ++i) {
            int k = mt * 16 + quad * 4 + i;
            pkW3[mt][i] = f2bf_pk(W3[k], W3[64 + k]);
        }
#pragma unroll
        for (int p2 = 0; p2 < 2; ++p2) {
            int k = mt * 16 + quad * 4 + 2 * p2;
            pkB2[mt][p2] = f2bf_pk(b2[k], b2[k + 1]);
        }
    }
    const float b30 = b3[0], b31 = b3[1];
    const f32x4 zero4 = {0.f, 0.f, 0.f, 0.f};

    for (int t = wid; t < ntiles; t += nwaves) {
        int row = t * 16 + col;
        int rl = row < B ? row : B - 1;
        float z0 = zin[3 * rl + 0];
        float z1 = zin[3 * rl + 1];

        f32x4 accH[4], accU[4], accV[4];

#pragma unroll
        for (int jt = 0; jt < 2; ++jt) {
            // ---- phase 1: layer-1 (branch-free elu) -> B-fragments ----
            i32x4 ah, au, av;
#pragma unroll
            for (int p2 = 0; p2 < 4; ++p2) {
                int pa = pkW1[jt][2 * p2];
                int pb = pkW1[jt][2 * p2 + 1];
                int pc = pkB1[jt][p2];
                float w0a = bf_lo(pa), w1a = bf_hi(pa);
                float w0b = bf_lo(pb), w1b = bf_hi(pb);
                float a0 = fmaf(w0a, z0, fmaf(w1a, z1, bf_lo(pc)));
                float a1 = fmaf(w0b, z0, fmaf(w1b, z1, bf_hi(pc)));
                float e0 = __expf(fminf(a0, 0.f));             // elu'
                float e1 = __expf(fminf(a1, 0.f));
                float h0 = fmaxf(a0, 0.f) + (e0 - 1.f);        // elu
                float h1 = fmaxf(a1, 0.f) + (e1 - 1.f);
                ah[p2] = f2bf_pk(h0, h1);
                au[p2] = f2bf_pk(e0 * w0a, e1 * w0b);
                av[p2] = f2bf_pk(e0 * w1a, e1 * w1b);
            }
            bf16x8 bh = __builtin_bit_cast(bf16x8, ah);
            bf16x8 bu = __builtin_bit_cast(bf16x8, au);
            bf16x8 bv = __builtin_bit_cast(bf16x8, av);

            // ---- phase 2: MFMA k-step jt for all 4 mtiles ----
#pragma unroll
            for (int mt = 0; mt < 4; ++mt) {
                accH[mt] = __builtin_amdgcn_mfma_f32_16x16x32_bf16(
                    aW2[mt][jt], bh, jt == 0 ? zero4 : accH[mt], 0, 0, 0);
                accU[mt] = __builtin_amdgcn_mfma_f32_16x16x32_bf16(
                    aW2[mt][jt], bu, jt == 0 ? zero4 : accU[mt], 0, 0, 0);
                accV[mt] = __builtin_amdgcn_mfma_f32_16x16x32_bf16(
                    aW2[mt][jt], bv, jt == 0 ? zero4 : accV[mt], 0, 0, 0);
            }
        }

        // ---- phase 3: elu + W3 fold, in-lane over this lane's 16 k's ----
        float o0 = 0.f, o1 = 0.f, trc = 0.f;
#pragma unroll
        for (int mt = 0; mt < 4; ++mt)
#pragma unroll
            for (int i = 0; i < 4; ++i) {
                int pw = pkW3[mt][i];
                float w30 = bf_lo(pw), w31 = bf_hi(pw);
                int pb = pkB2[mt][i >> 1];
                float bb = (i & 1) ? bf_hi(pb) : bf_lo(pb);   // const-folded
                float a2  = accH[mt][i] + bb;
                float ex2 = __expf(fminf(a2, 0.f));
                float hh  = fmaxf(a2, 0.f) + (ex2 - 1.f);
                o0  = fmaf(w30, hh, o0);
                o1  = fmaf(w31, hh, o1);
                trc = fmaf(ex2, fmaf(w30, accU[mt][i], w31 * accV[mt][i]), trc);
            }

        // ---- cross-quad reduction (k spans quads): 2 butterfly stages ----
        o0  += __shfl_xor(o0, 16);  o0  += __shfl_xor(o0, 32);
        o1  += __shfl_xor(o1, 16);  o1  += __shfl_xor(o1, 32);
        trc += __shfl_xor(trc, 16); trc += __shfl_xor(trc, 32);

        if (lane < 16 && row < B) {
            out[3 * row + 0] = o0 + b30;
            out[3 * row + 1] = o1 + b31;
            out[3 * row + 2] = -trc;
        }
    }
}

extern "C" void kernel_launch(void* const* d_in, const int* in_sizes, int n_in,
                              void* d_out, int out_size, void* d_ws, size_t ws_size,
                              hipStream_t stream) {
    // d_in: 0=t(unused) 1=z_and_logp 2=W1 3=b1 4=W2 5=b2 6=W3 7=b3
    const float* zin = (const float*)d_in[1];
    const float* W1  = (const float*)d_in[2];
    const float* b1  = (const float*)d_in[3];
    const float* W2  = (const float*)d_in[4];
    const float* b2  = (const float*)d_in[5];
    const float* W3  = (const float*)d_in[6];
    const float* b3  = (const float*)d_in[7];
    float* out = (float*)d_out;

    int B = in_sizes[1] / 3;
    int ntiles = (B + 15) / 16;
    // 768 blocks x 4 waves = 3072 waves = exactly 3/EU resident on 256 CUs
    odefunc_mfma<<<768, 256, 0, stream>>>(zin, W1, b1, W2, b2, W3, b3,
                                          out, B, ntiles);
}

// Round 11
// 148.661 us; speedup vs baseline: 1.2130x; 1.2130x over previous
//
#include <hip/hip_runtime.h>
#include <hip/hip_bf16.h>

// ODEFunc CNF dynamics, B=1e6 rows, H=64:
//   h1 = elu(W1 z + b1); [h2|u2|v2] = [h1|u|v] W2^T; out01 = W3 elu(h2)+b3;
//   trace = W3[0,:]*(elu'(h2)*u2) + W3[1,:]*(elu'(h2)*v2); out[:,2] = -trace
//
// R11 = synthesis. Allocator rule (observed R1/R6/R8/R10): with MFMA, the
// unified file splits ~50/50 arch/AGPR; at 2 waves/EU that's 128 arch.
// 3 waves/EU (85 arch) is unreachable: R8 critical-path reloads (105us),
// R10 spill (123us). So: 2 waves/EU + kill the per-tile z-load stall.
//   - R10's bf16-packed persistent consts: layer-1 24 regs, epilogue 24 regs
//     (unpack = 1 shift/and; rel err 0.4%, threshold has 4.5x room)
//   - R9's z software-prefetch — now SPILL-FREE because packing freed ~45
//     arch regs (R9 spilled 2.6MB at R6's zero-headroom 128).
//   - jt-interleaved phase1/MFMA (B-frag liveness 12 not 24).
// Arch demand ~115 <= 128. Accs 48 live in AGPR half (MFMA-native).
// Grid 512x256 = 2048 waves = exactly resident at 2/EU; ~30 tiles/wave.
// MFMA layout (R6-validated): A=W2 block A[m=lane&15][k=quad*8+jj]; B=[h|u|v]^T
// in-register; D[k][row]: row=lane&15, k=mt*16+quad*4+reg; W3-fold in-lane
// over 16 k + 2 shfl_xor stages. No LDS. Spill tripwire: WRITE==11718.75KB.

typedef short bf16x8 __attribute__((ext_vector_type(8)));
typedef float f32x4  __attribute__((ext_vector_type(4)));
typedef int   i32x4  __attribute__((ext_vector_type(4)));

#if defined(__has_builtin)
#if __has_builtin(__builtin_amdgcn_cvt_pk_bf16_f32)
#define HAVE_PK_BF16 1
#endif
#endif

#ifdef HAVE_PK_BF16
typedef __bf16 bf16x2_t __attribute__((ext_vector_type(2)));
static __device__ __forceinline__ int f2bf_pk(float a, float b) {
    bf16x2_t r = __builtin_amdgcn_cvt_pk_bf16_f32(a, b);   // lo=a, hi=b
    return __builtin_bit_cast(int, r);
}
#else
static __device__ __forceinline__ int f2bf_pk(float a, float b) {
    unsigned ua = __builtin_bit_cast(unsigned, a);
    unsigned ub = __builtin_bit_cast(unsigned, b);
    ua = (ua + 0x7FFFu + ((ua >> 16) & 1u)) >> 16;
    ub = (ub + 0x7FFFu + ((ub >> 16) & 1u)) & 0xFFFF0000u;
    return (int)(ua | ub);
}
#endif

// bf16 pair -> f32 (exact): lo = shift, hi = mask
static __device__ __forceinline__ float bf_lo(int p) {
    return __builtin_bit_cast(float, (unsigned)p << 16);
}
static __device__ __forceinline__ float bf_hi(int p) {
    return __builtin_bit_cast(float, (unsigned)p & 0xFFFF0000u);
}

__global__ __launch_bounds__(256) __attribute__((amdgpu_waves_per_eu(2, 2)))
void odefunc_mfma(const float* __restrict__ zin,
                  const float* __restrict__ W1, const float* __restrict__ b1,
                  const float* __restrict__ W2, const float* __restrict__ b2,
                  const float* __restrict__ W3, const float* __restrict__ b3,
                  float* __restrict__ out, int B, int ntiles)
{
    const int lane = threadIdx.x & 63;
    const int quad = lane >> 4;      // 0..3
    const int col  = lane & 15;      // row-within-tile (B/D n-index)

    const int wid    = blockIdx.x * (blockDim.x >> 6) + (threadIdx.x >> 6);
    const int nwaves = gridDim.x * (blockDim.x >> 6);

    // ---- Persistent: W2 as A-operand fragments (4 mtiles x 2 jtiles) ----
    bf16x8 aW2[4][2];
#pragma unroll
    for (int mt = 0; mt < 4; ++mt)
#pragma unroll
        for (int jt = 0; jt < 2; ++jt) {
            const float* p = W2 + (mt * 16 + col) * 64 + jt * 32 + quad * 8;
            i32x4 w;
#pragma unroll
            for (int p2 = 0; p2 < 4; ++p2)
                w[p2] = f2bf_pk(p[2 * p2], p[2 * p2 + 1]);
            aW2[mt][jt] = __builtin_bit_cast(bf16x8, w);
        }

    // ---- Persistent, packed bf16: layer-1 consts (16 j's/lane): 24 regs ----
    int pkW1[2][8];   // (w0,w1) per j
    int pkB1[2][4];   // (b1_j0, b1_j1) per pair
#pragma unroll
    for (int jt = 0; jt < 2; ++jt) {
#pragma unroll
        for (int jj = 0; jj < 8; ++jj) {
            int j = jt * 32 + quad * 8 + jj;
            pkW1[jt][jj] = f2bf_pk(W1[2 * j], W1[2 * j + 1]);
        }
#pragma unroll
        for (int p2 = 0; p2 < 4; ++p2) {
            int j = jt * 32 + quad * 8 + 2 * p2;
            pkB1[jt][p2] = f2bf_pk(b1[j], b1[j + 1]);
        }
    }

    // ---- Persistent, packed bf16: epilogue consts (16 k's/lane): 24 regs ----
    int pkW3[4][4];   // (W3[0,k], W3[1,k]) per k
    int pkB2[4][2];   // (b2_k0, b2_k1) per pair
#pragma unroll
    for (int mt = 0; mt < 4; ++mt) {
#pragma unroll
        for (int i = 0; i < 4; ++i) {
            int k = mt * 16 + quad * 4 + i;
            pkW3[mt][i] = f2bf_pk(W3[k], W3[64 + k]);
        }
#pragma unroll
        for (int p2 = 0; p2 < 2; ++p2) {
            int k = mt * 16 + quad * 4 + 2 * p2;
            pkB2[mt][p2] = f2bf_pk(b2[k], b2[k + 1]);
        }
    }
    const float b30 = b3[0], b31 = b3[1];
    const f32x4 zero4 = {0.f, 0.f, 0.f, 0.f};

    // ---- Software pipeline: prefetch z for the first tile ----
    int t = wid;
    float z0n = 0.f, z1n = 0.f;
    if (t < ntiles) {
        int row = t * 16 + col;
        int rl = row < B ? row : B - 1;
        z0n = zin[3 * rl + 0];
        z1n = zin[3 * rl + 1];
    }

    for (; t < ntiles; t += nwaves) {
        int row = t * 16 + col;
        float z0 = z0n, z1 = z1n;

        // Issue next tile's z load NOW (uniform branch); consumed next iter.
        int tn = t + nwaves;
        if (tn < ntiles) {
            int rown = tn * 16 + col;
            int rln = rown < B ? rown : B - 1;
            z0n = zin[3 * rln + 0];
            z1n = zin[3 * rln + 1];
        }

        f32x4 accH[4], accU[4], accV[4];

#pragma unroll
        for (int jt = 0; jt < 2; ++jt) {
            // ---- phase 1: layer-1 (branch-free elu) -> B-fragments ----
            i32x4 ah, au, av;
#pragma unroll
            for (int p2 = 0; p2 < 4; ++p2) {
                int pa = pkW1[jt][2 * p2];
                int pb = pkW1[jt][2 * p2 + 1];
                int pc = pkB1[jt][p2];
                float w0a = bf_lo(pa), w1a = bf_hi(pa);
                float w0b = bf_lo(pb), w1b = bf_hi(pb);
                float a0 = fmaf(w0a, z0, fmaf(w1a, z1, bf_lo(pc)));
                float a1 = fmaf(w0b, z0, fmaf(w1b, z1, bf_hi(pc)));
                float e0 = __expf(fminf(a0, 0.f));             // elu'
                float e1 = __expf(fminf(a1, 0.f));
                float h0 = fmaxf(a0, 0.f) + (e0 - 1.f);        // elu
                float h1 = fmaxf(a1, 0.f) + (e1 - 1.f);
                ah[p2] = f2bf_pk(h0, h1);
                au[p2] = f2bf_pk(e0 * w0a, e1 * w0b);
                av[p2] = f2bf_pk(e0 * w1a, e1 * w1b);
            }
            bf16x8 bh = __builtin_bit_cast(bf16x8, ah);
            bf16x8 bu = __builtin_bit_cast(bf16x8, au);
            bf16x8 bv = __builtin_bit_cast(bf16x8, av);

            // ---- phase 2: MFMA k-step jt for all 4 mtiles ----
#pragma unroll
            for (int mt = 0; mt < 4; ++mt) {
                accH[mt] = __builtin_amdgcn_mfma_f32_16x16x32_bf16(
                    aW2[mt][jt], bh, jt == 0 ? zero4 : accH[mt], 0, 0, 0);
                accU[mt] = __builtin_amdgcn_mfma_f32_16x16x32_bf16(
                    aW2[mt][jt], bu, jt == 0 ? zero4 : accU[mt], 0, 0, 0);
                accV[mt] = __builtin_amdgcn_mfma_f32_16x16x32_bf16(
                    aW2[mt][jt], bv, jt == 0 ? zero4 : accV[mt], 0, 0, 0);
            }
        }

        // ---- phase 3: elu + W3 fold, in-lane over this lane's 16 k's ----
        float o0 = 0.f, o1 = 0.f, trc = 0.f;
#pragma unroll
        for (int mt = 0; mt < 4; ++mt)
#pragma unroll
            for (int i = 0; i < 4; ++i) {
                int pw = pkW3[mt][i];
                float w30 = bf_lo(pw), w31 = bf_hi(pw);
                int pb = pkB2[mt][i >> 1];
                float bb = (i & 1) ? bf_hi(pb) : bf_lo(pb);   // const-folded
                float a2  = accH[mt][i] + bb;
                float ex2 = __expf(fminf(a2, 0.f));
                float hh  = fmaxf(a2, 0.f) + (ex2 - 1.f);
                o0  = fmaf(w30, hh, o0);
                o1  = fmaf(w31, hh, o1);
                trc = fmaf(ex2, fmaf(w30, accU[mt][i], w31 * accV[mt][i]), trc);
            }

        // ---- cross-quad reduction (k spans quads): 2 butterfly stages ----
        o0  += __shfl_xor(o0, 16);  o0  += __shfl_xor(o0, 32);
        o1  += __shfl_xor(o1, 16);  o1  += __shfl_xor(o1, 32);
        trc += __shfl_xor(trc, 16); trc += __shfl_xor(trc, 32);

        if (lane < 16 && row < B) {
            out[3 * row + 0] = o0 + b30;
            out[3 * row + 1] = o1 + b31;
            out[3 * row + 2] = -trc;
        }
    }
}

extern "C" void kernel_launch(void* const* d_in, const int* in_sizes, int n_in,
                              void* d_out, int out_size, void* d_ws, size_t ws_size,
                              hipStream_t stream) {
    // d_in: 0=t(unused) 1=z_and_logp 2=W1 3=b1 4=W2 5=b2 6=W3 7=b3
    const float* zin = (const float*)d_in[1];
    const float* W1  = (const float*)d_in[2];
    const float* b1  = (const float*)d_in[3];
    const float* W2  = (const float*)d_in[4];
    const float* b2  = (const float*)d_in[5];
    const float* W3  = (const float*)d_in[6];
    const float* b3  = (const float*)d_in[7];
    float* out = (float*)d_out;

    int B = in_sizes[1] / 3;
    int ntiles = (B + 15) / 16;
    // 512 blocks x 4 waves = 2048 waves = exactly resident at 2/EU on 256 CU;
    // ~30 tiles/wave keeps the z-prefetch pipeline primed.
    odefunc_mfma<<<512, 256, 0, stream>>>(zin, W1, b1, W2, b2, W3, b3,
                                          out, B, ntiles);
}